// Round 2
// baseline (478.448 us; speedup 1.0000x reference)
//
#include <hip/hip_runtime.h>
#include <hip/hip_bf16.h>

#define E_EDGES 800000
#define NNODES  50000
#define HID     128

typedef __bf16 bf16x8 __attribute__((ext_vector_type(8)));
typedef float  f32x4  __attribute__((ext_vector_type(4)));
typedef unsigned short ushortx8 __attribute__((ext_vector_type(8)));

__device__ __forceinline__ unsigned short f2bf(float f) {
    union { float f; unsigned u; } v; v.f = f;
    unsigned r = v.u + 0x7FFFu + ((v.u >> 16) & 1u);
    return (unsigned short)(r >> 16);
}

__device__ __forceinline__ float silu(float x) {
    return x / (1.0f + __expf(-x));
}

// ---- weight packing (same layouts as round 1, which validated) ----
__global__ void pack_weights(const float* __restrict__ W1, const float* __restrict__ b1,
                             const float* __restrict__ W2, const float* __restrict__ b2,
                             unsigned short* __restrict__ W1p, unsigned short* __restrict__ W2p,
                             float4* __restrict__ Wext) {
    int i = blockIdx.x * 256 + threadIdx.x;
    if (i < 32768) {
        int j = i & 7, lane = (i >> 3) & 63, nt = (i >> 9) & 7, kc = i >> 12;
        int n = lane & 15, quad = lane >> 4;
        int k = kc * 32 + quad * 8 + j;
        W1p[i] = f2bf(W1[(nt * 16 + n) * 258 + k]);
    } else if (i < 32768 + 16384) {
        int t = i - 32768;
        int j = t & 7, lane = (t >> 3) & 63, nt = (t >> 9) & 7, kc = t >> 12;
        int n = lane & 15, quad = lane >> 4;
        int p = kc * 32 + quad * 8 + j;
        int f = (p & 7) * 16 + (p >> 3);
        W2p[t] = f2bf(W2[(nt * 16 + n) * 128 + f]);
    } else if (i < 32768 + 16384 + 128) {
        int c = i - (32768 + 16384);
        Wext[c] = make_float4(W1[c * 258 + 256], W1[c * 258 + 257], b1[c], b2[c]);
    }
}

// h (fp32) -> h2 (bf16), 8 elements per thread
__global__ void convert_h(const float* __restrict__ h, unsigned short* __restrict__ h2) {
    int i = blockIdx.x * 256 + threadIdx.x;   // 800000 threads
    const float4* p = (const float4*)(h + i * 8);
    float4 lo = p[0], hi = p[1];
    ushortx8 u;
    u[0] = f2bf(lo.x); u[1] = f2bf(lo.y); u[2] = f2bf(lo.z); u[3] = f2bf(lo.w);
    u[4] = f2bf(hi.x); u[5] = f2bf(hi.y); u[6] = f2bf(hi.z); u[7] = f2bf(hi.w);
    *(ushortx8*)(h2 + i * 8) = u;
}

__global__ void init_out(const float* __restrict__ coord, float* __restrict__ out, int n) {
    int i = blockIdx.x * 256 + threadIdx.x;
    if (i < n) out[i] = coord[i];
}

template <bool USE_H2>
__launch_bounds__(256)
__global__ void edge_kernel(const float* __restrict__ h, const unsigned short* __restrict__ h2,
                            const int* __restrict__ ei,
                            const float* __restrict__ cdiff, const float* __restrict__ eattr,
                            const ushortx8* __restrict__ W1p, const ushortx8* __restrict__ W2p,
                            const float4* __restrict__ Wext, const float* __restrict__ W3,
                            float* __restrict__ out) {
    __shared__ __align__(16) unsigned short x1[4][32][136]; // 272B stride: 16B aligned, 2-way banks
    __shared__ float sbuf[4][32];

    const int w    = threadIdx.x >> 6;
    const int lane = threadIdx.x & 63;
    const int n    = lane & 15;
    const int quad = lane >> 4;
    const int ebase = (blockIdx.x * 4 + w) * 32;

    // wave-local edge data: every lane loads edge (lane&31); shuffles distribute
    const int el = ebase + (lane & 31);
    const int ri = ei[el];
    const int ci = ei[E_EDGES + el];
    const float2 ea = *(const float2*)(eattr + 2 * (long)el);

    int nodeR[2], nodeC[2];
#pragma unroll
    for (int mt = 0; mt < 2; ++mt) {
        nodeR[mt] = __shfl(ri, mt * 16 + n, 64);
        nodeC[mt] = __shfl(ci, mt * 16 + n, 64);
    }

    const f32x4 zero = { 0.f, 0.f, 0.f, 0.f };
    f32x4 acc[2][8];
#pragma unroll
    for (int mt = 0; mt < 2; ++mt)
#pragma unroll
        for (int nt = 0; nt < 8; ++nt) acc[mt][nt] = zero;

    // ---- layer 1: [32 edges, 256] @ W1[:, :256]^T ----
#pragma unroll
    for (int kc = 0; kc < 8; ++kc) {
        bf16x8 afrag[2];
#pragma unroll
        for (int mt = 0; mt < 2; ++mt) {
            int node = (kc < 4) ? nodeR[mt] : nodeC[mt];
            if constexpr (USE_H2) {
                afrag[mt] = __builtin_bit_cast(bf16x8,
                    *(const ushortx8*)(h2 + (long)node * HID + (kc & 3) * 32 + quad * 8));
            } else {
                const float* p = h + (long)node * HID + (kc & 3) * 32 + quad * 8;
                float4 lo = *(const float4*)p;
                float4 hi = *(const float4*)(p + 4);
                ushortx8 u;
                u[0] = f2bf(lo.x); u[1] = f2bf(lo.y); u[2] = f2bf(lo.z); u[3] = f2bf(lo.w);
                u[4] = f2bf(hi.x); u[5] = f2bf(hi.y); u[6] = f2bf(hi.z); u[7] = f2bf(hi.w);
                afrag[mt] = __builtin_bit_cast(bf16x8, u);
            }
        }
#pragma unroll
        for (int nt = 0; nt < 8; ++nt) {
            bf16x8 bfrag = __builtin_bit_cast(bf16x8, W1p[(kc * 8 + nt) * 64 + lane]);
            acc[0][nt] = __builtin_amdgcn_mfma_f32_16x16x32_bf16(afrag[0], bfrag, acc[0][nt], 0, 0, 0);
            acc[1][nt] = __builtin_amdgcn_mfma_f32_16x16x32_bf16(afrag[1], bfrag, acc[1][nt], 0, 0, 0);
        }
    }

    // epilogue 1: + b1 + edge_attr @ W1[:, 256:258], silu, bf16 -> LDS (permuted features)
    float4 wx[8];
#pragma unroll
    for (int nt = 0; nt < 8; ++nt) wx[nt] = Wext[nt * 16 + n];

#pragma unroll
    for (int mt = 0; mt < 2; ++mt) {
#pragma unroll
        for (int r = 0; r < 4; ++r) {
            int m = mt * 16 + quad * 4 + r;
            float a0 = __shfl(ea.x, m, 64);
            float a1 = __shfl(ea.y, m, 64);
            ushortx8 u;
#pragma unroll
            for (int nt = 0; nt < 8; ++nt) {
                float v = acc[mt][nt][r] + wx[nt].z + a0 * wx[nt].x + a1 * wx[nt].y;
                u[nt] = f2bf(silu(v));
            }
            *(ushortx8*)&x1[w][m][n * 8] = u;  // position n*8+nt holds feature nt*16+n
        }
    }
    // wave-synchronous LDS fence (x1[w] touched only by wave w)
    asm volatile("s_waitcnt lgkmcnt(0)" ::: "memory");

    // ---- layer 2: [32, 128] @ W2^T (permuted-k packing matches LDS layout) ----
#pragma unroll
    for (int mt = 0; mt < 2; ++mt)
#pragma unroll
        for (int nt = 0; nt < 8; ++nt) acc[mt][nt] = zero;

#pragma unroll
    for (int kc = 0; kc < 4; ++kc) {
        bf16x8 afrag[2];
#pragma unroll
        for (int mt = 0; mt < 2; ++mt)
            afrag[mt] = __builtin_bit_cast(bf16x8, *(const ushortx8*)&x1[w][mt * 16 + n][kc * 32 + quad * 8]);
#pragma unroll
        for (int nt = 0; nt < 8; ++nt) {
            bf16x8 bfrag = __builtin_bit_cast(bf16x8, W2p[(kc * 8 + nt) * 64 + lane]);
            acc[0][nt] = __builtin_amdgcn_mfma_f32_16x16x32_bf16(afrag[0], bfrag, acc[0][nt], 0, 0, 0);
            acc[1][nt] = __builtin_amdgcn_mfma_f32_16x16x32_bf16(afrag[1], bfrag, acc[1][nt], 0, 0, 0);
        }
    }

    // epilogue 2 + layer 3: silu(acc + b2) . W3, butterfly over n
    float part[2][4] = { {0.f,0.f,0.f,0.f}, {0.f,0.f,0.f,0.f} };
#pragma unroll
    for (int nt = 0; nt < 8; ++nt) {
        float w3 = W3[nt * 16 + n];
        float bb2 = wx[nt].w;
#pragma unroll
        for (int mt = 0; mt < 2; ++mt)
#pragma unroll
            for (int r = 0; r < 4; ++r)
                part[mt][r] += silu(acc[mt][nt][r] + bb2) * w3;
    }
#pragma unroll
    for (int mask = 1; mask < 16; mask <<= 1)
#pragma unroll
        for (int mt = 0; mt < 2; ++mt)
#pragma unroll
            for (int r = 0; r < 4; ++r)
                part[mt][r] += __shfl_xor(part[mt][r], mask, 64);

    if (n == 0) {
#pragma unroll
        for (int mt = 0; mt < 2; ++mt)
#pragma unroll
            for (int r = 0; r < 4; ++r)
                sbuf[w][mt * 16 + quad * 4 + r] = part[mt][r];
    }
    asm volatile("s_waitcnt lgkmcnt(0)" ::: "memory");

    if (lane < 32) {
        int e = ebase + lane;
        float s = sbuf[w][lane];
        float ex = __expf(2.0f * s);
        float th = 1.0f - 2.0f / (ex + 1.0f);      // tanh, saturating
        float t = th * 0.15f;                      // *15 / 100
        float c0 = cdiff[3 * (long)e + 0];
        float c1 = cdiff[3 * (long)e + 1];
        float c2 = cdiff[3 * (long)e + 2];
        atomicAdd(&out[ri * 3 + 0], c0 * t);
        atomicAdd(&out[ri * 3 + 1], c1 * t);
        atomicAdd(&out[ri * 3 + 2], c2 * t);
    }
}

extern "C" void kernel_launch(void* const* d_in, const int* in_sizes, int n_in,
                              void* d_out, int out_size, void* d_ws, size_t ws_size,
                              hipStream_t stream) {
    const float* h     = (const float*)d_in[0];
    const float* coord = (const float*)d_in[1];
    const int*   ei    = (const int*)d_in[2];
    const float* cdiff = (const float*)d_in[3];
    const float* eattr = (const float*)d_in[4];
    const float* W1    = (const float*)d_in[5];
    const float* b1    = (const float*)d_in[6];
    const float* W2    = (const float*)d_in[7];
    const float* b2    = (const float*)d_in[8];
    const float* W3    = (const float*)d_in[9];
    float* out = (float*)d_out;

    unsigned short* W1p = (unsigned short*)d_ws;
    unsigned short* W2p = W1p + 32768;
    float4* Wext = (float4*)(W2p + 16384);
    unsigned short* h2 = (unsigned short*)((char*)d_ws + 32768 * 2 + 16384 * 2 + 128 * 16);
    const size_t need = 32768ull * 2 + 16384 * 2 + 128 * 16 + (size_t)NNODES * HID * 2;

    pack_weights<<<(32768 + 16384 + 128 + 255) / 256, 256, 0, stream>>>(W1, b1, W2, b2, W1p, W2p, Wext);
    init_out<<<(3 * NNODES + 255) / 256, 256, 0, stream>>>(coord, out, 3 * NNODES);

    if (ws_size >= need) {
        convert_h<<<(NNODES * HID / 8 + 255) / 256, 256, 0, stream>>>(h, h2);
        edge_kernel<true><<<E_EDGES / 128, 256, 0, stream>>>(h, h2, ei, cdiff, eattr,
                                                             (const ushortx8*)W1p, (const ushortx8*)W2p,
                                                             (const float4*)Wext, W3, out);
    } else {
        edge_kernel<false><<<E_EDGES / 128, 256, 0, stream>>>(h, h2, ei, cdiff, eattr,
                                                              (const ushortx8*)W1p, (const ushortx8*)W2p,
                                                              (const float4*)Wext, W3, out);
    }
}

// Round 3
// 477.814 us; speedup vs baseline: 1.0013x; 1.0013x over previous
//
#include <hip/hip_runtime.h>
#include <hip/hip_bf16.h>

#define E_EDGES 800000
#define NNODES  50000
#define HID     128

typedef __bf16 bf16x8 __attribute__((ext_vector_type(8)));
typedef float  f32x4  __attribute__((ext_vector_type(4)));
typedef unsigned short ushortx8 __attribute__((ext_vector_type(8)));

__device__ __forceinline__ unsigned short f2bf(float f) {
    union { float f; unsigned u; } v; v.f = f;
    unsigned r = v.u + 0x7FFFu + ((v.u >> 16) & 1u);
    return (unsigned short)(r >> 16);
}

__device__ __forceinline__ float silu(float x) {
    return x / (1.0f + __expf(-x));
}

// ---- weight packing (validated layouts) ----
__global__ void pack_weights(const float* __restrict__ W1, const float* __restrict__ b1,
                             const float* __restrict__ W2, const float* __restrict__ b2,
                             unsigned short* __restrict__ W1p, unsigned short* __restrict__ W2p,
                             float4* __restrict__ Wext) {
    int i = blockIdx.x * 256 + threadIdx.x;
    if (i < 32768) {
        int j = i & 7, lane = (i >> 3) & 63, nt = (i >> 9) & 7, kc = i >> 12;
        int n = lane & 15, quad = lane >> 4;
        int k = kc * 32 + quad * 8 + j;
        W1p[i] = f2bf(W1[(nt * 16 + n) * 258 + k]);
    } else if (i < 32768 + 16384) {
        int t = i - 32768;
        int j = t & 7, lane = (t >> 3) & 63, nt = (t >> 9) & 7, kc = t >> 12;
        int n = lane & 15, quad = lane >> 4;
        int p = kc * 32 + quad * 8 + j;
        int f = (p & 7) * 16 + (p >> 3);
        W2p[t] = f2bf(W2[(nt * 16 + n) * 128 + f]);
    } else if (i < 32768 + 16384 + 128) {
        int c = i - (32768 + 16384);
        Wext[c] = make_float4(W1[c * 258 + 256], W1[c * 258 + 257], b1[c], b2[c]);
    }
}

// h (fp32) -> h2 (bf16), 8 elements per thread
__global__ void convert_h(const float* __restrict__ h, unsigned short* __restrict__ h2) {
    int i = blockIdx.x * 256 + threadIdx.x;   // 800000 threads
    const float4* p = (const float4*)(h + i * 8);
    float4 lo = p[0], hi = p[1];
    ushortx8 u;
    u[0] = f2bf(lo.x); u[1] = f2bf(lo.y); u[2] = f2bf(lo.z); u[3] = f2bf(lo.w);
    u[4] = f2bf(hi.x); u[5] = f2bf(hi.y); u[6] = f2bf(hi.z); u[7] = f2bf(hi.w);
    *(ushortx8*)(h2 + i * 8) = u;
}

__global__ void init_out(const float* __restrict__ coord, float* __restrict__ out, int n) {
    int i = blockIdx.x * 256 + threadIdx.x;
    if (i < n) out[i] = coord[i];
}

template <bool USE_H2>
__launch_bounds__(256)
__global__ void edge_kernel(const float* __restrict__ h, const unsigned short* __restrict__ h2,
                            const int* __restrict__ ei,
                            const float* __restrict__ cdiff, const float* __restrict__ eattr,
                            const ushortx8* __restrict__ W1p, const ushortx8* __restrict__ W2p,
                            const float4* __restrict__ Wext, const float* __restrict__ W3,
                            float* __restrict__ out) {
    __shared__ __align__(16) unsigned short x1[4][32][136]; // 272B stride, 2-way banks (free)
    __shared__ int   rowi[4][32];
    __shared__ int   coli[4][32];
    __shared__ float ea0[4][32];
    __shared__ float ea1[4][32];
    __shared__ float sbuf[4][32];

    const int w    = threadIdx.x >> 6;
    const int lane = threadIdx.x & 63;
    const int n    = lane & 15;
    const int quad = lane >> 4;
    const int ebase = (blockIdx.x * 4 + w) * 32;

    if (lane < 32) {
        int e = ebase + lane;
        rowi[w][lane] = ei[e];
        coli[w][lane] = ei[E_EDGES + e];
        const float2 ea = *(const float2*)(eattr + 2 * (long)e);
        ea0[w][lane] = ea.x;
        ea1[w][lane] = ea.y;
    }
    __syncthreads();

    int nodeR[2] = { rowi[w][n], rowi[w][16 + n] };
    int nodeC[2] = { coli[w][n], coli[w][16 + n] };

    const f32x4 zero = { 0.f, 0.f, 0.f, 0.f };
    f32x4 acc[2][8];
#pragma unroll
    for (int mt = 0; mt < 2; ++mt)
#pragma unroll
        for (int nt = 0; nt < 8; ++nt) acc[mt][nt] = zero;

    // ---- layer 1: [32 edges, 256] @ W1[:, :256]^T ----
#pragma unroll
    for (int kc = 0; kc < 8; ++kc) {
        bf16x8 afrag[2];
#pragma unroll
        for (int mt = 0; mt < 2; ++mt) {
            int node = (kc < 4) ? nodeR[mt] : nodeC[mt];
            if constexpr (USE_H2) {
                afrag[mt] = __builtin_bit_cast(bf16x8,
                    *(const ushortx8*)(h2 + (long)node * HID + (kc & 3) * 32 + quad * 8));
            } else {
                const float* p = h + (long)node * HID + (kc & 3) * 32 + quad * 8;
                float4 lo = *(const float4*)p;
                float4 hi = *(const float4*)(p + 4);
                ushortx8 u;
                u[0] = f2bf(lo.x); u[1] = f2bf(lo.y); u[2] = f2bf(lo.z); u[3] = f2bf(lo.w);
                u[4] = f2bf(hi.x); u[5] = f2bf(hi.y); u[6] = f2bf(hi.z); u[7] = f2bf(hi.w);
                afrag[mt] = __builtin_bit_cast(bf16x8, u);
            }
        }
#pragma unroll
        for (int nt = 0; nt < 8; ++nt) {
            bf16x8 bfrag = __builtin_bit_cast(bf16x8, W1p[(kc * 8 + nt) * 64 + lane]);
            acc[0][nt] = __builtin_amdgcn_mfma_f32_16x16x32_bf16(afrag[0], bfrag, acc[0][nt], 0, 0, 0);
            acc[1][nt] = __builtin_amdgcn_mfma_f32_16x16x32_bf16(afrag[1], bfrag, acc[1][nt], 0, 0, 0);
        }
    }

    // epilogue 1: + b1 + edge_attr @ W1[:, 256:258], silu, bf16 -> LDS (permuted features)
    // Only b2 (wx.w) survives past this block -> shorter live ranges, lower VGPR.
    float b2v[8];
    {
        float4 wx[8];
#pragma unroll
        for (int nt = 0; nt < 8; ++nt) wx[nt] = Wext[nt * 16 + n];
#pragma unroll
        for (int nt = 0; nt < 8; ++nt) b2v[nt] = wx[nt].w;

#pragma unroll
        for (int mt = 0; mt < 2; ++mt) {
#pragma unroll
            for (int r = 0; r < 4; ++r) {
                int m = mt * 16 + quad * 4 + r;
                float a0 = ea0[w][m], a1 = ea1[w][m];
                ushortx8 u;
#pragma unroll
                for (int nt = 0; nt < 8; ++nt) {
                    float v = acc[mt][nt][r] + wx[nt].z + a0 * wx[nt].x + a1 * wx[nt].y;
                    u[nt] = f2bf(silu(v));
                }
                *(ushortx8*)&x1[w][m][n * 8] = u;  // position n*8+nt holds feature nt*16+n
            }
        }
    }
    __syncthreads();

    // ---- layer 2: [32, 128] @ W2^T (permuted-k packing matches LDS layout) ----
#pragma unroll
    for (int mt = 0; mt < 2; ++mt)
#pragma unroll
        for (int nt = 0; nt < 8; ++nt) acc[mt][nt] = zero;

#pragma unroll
    for (int kc = 0; kc < 4; ++kc) {
        bf16x8 afrag[2];
#pragma unroll
        for (int mt = 0; mt < 2; ++mt)
            afrag[mt] = __builtin_bit_cast(bf16x8, *(const ushortx8*)&x1[w][mt * 16 + n][kc * 32 + quad * 8]);
#pragma unroll
        for (int nt = 0; nt < 8; ++nt) {
            bf16x8 bfrag = __builtin_bit_cast(bf16x8, W2p[(kc * 8 + nt) * 64 + lane]);
            acc[0][nt] = __builtin_amdgcn_mfma_f32_16x16x32_bf16(afrag[0], bfrag, acc[0][nt], 0, 0, 0);
            acc[1][nt] = __builtin_amdgcn_mfma_f32_16x16x32_bf16(afrag[1], bfrag, acc[1][nt], 0, 0, 0);
        }
    }

    // epilogue 2 + layer 3: silu(acc + b2) . W3, butterfly over n
    float part[2][4] = { {0.f,0.f,0.f,0.f}, {0.f,0.f,0.f,0.f} };
#pragma unroll
    for (int nt = 0; nt < 8; ++nt) {
        float w3 = W3[nt * 16 + n];
#pragma unroll
        for (int mt = 0; mt < 2; ++mt)
#pragma unroll
            for (int r = 0; r < 4; ++r)
                part[mt][r] += silu(acc[mt][nt][r] + b2v[nt]) * w3;
    }
#pragma unroll
    for (int mask = 1; mask < 16; mask <<= 1)
#pragma unroll
        for (int mt = 0; mt < 2; ++mt)
#pragma unroll
            for (int r = 0; r < 4; ++r)
                part[mt][r] += __shfl_xor(part[mt][r], mask, 64);

    if (n == 0) {
#pragma unroll
        for (int mt = 0; mt < 2; ++mt)
#pragma unroll
            for (int r = 0; r < 4; ++r)
                sbuf[w][mt * 16 + quad * 4 + r] = part[mt][r];
    }
    __syncthreads();

    if (lane < 32) {
        int e = ebase + lane;
        float s = sbuf[w][lane];
        float ex = __expf(2.0f * s);
        float th = 1.0f - 2.0f / (ex + 1.0f);      // tanh, saturating
        float t = th * 0.15f;                      // *15 (COORDS_RANGE) / 100 (NORM_FACTOR)
        float c0 = cdiff[3 * (long)e + 0];
        float c1 = cdiff[3 * (long)e + 1];
        float c2 = cdiff[3 * (long)e + 2];
        int r = rowi[w][lane];
        atomicAdd(&out[r * 3 + 0], c0 * t);
        atomicAdd(&out[r * 3 + 1], c1 * t);
        atomicAdd(&out[r * 3 + 2], c2 * t);
    }
}

extern "C" void kernel_launch(void* const* d_in, const int* in_sizes, int n_in,
                              void* d_out, int out_size, void* d_ws, size_t ws_size,
                              hipStream_t stream) {
    const float* h     = (const float*)d_in[0];
    const float* coord = (const float*)d_in[1];
    const int*   ei    = (const int*)d_in[2];
    const float* cdiff = (const float*)d_in[3];
    const float* eattr = (const float*)d_in[4];
    const float* W1    = (const float*)d_in[5];
    const float* b1    = (const float*)d_in[6];
    const float* W2    = (const float*)d_in[7];
    const float* b2    = (const float*)d_in[8];
    const float* W3    = (const float*)d_in[9];
    float* out = (float*)d_out;

    unsigned short* W1p = (unsigned short*)d_ws;
    unsigned short* W2p = W1p + 32768;
    float4* Wext = (float4*)(W2p + 16384);
    unsigned short* h2 = (unsigned short*)((char*)d_ws + 32768 * 2 + 16384 * 2 + 128 * 16);
    const size_t need = 32768ull * 2 + 16384 * 2 + 128 * 16 + (size_t)NNODES * HID * 2;

    pack_weights<<<(32768 + 16384 + 128 + 255) / 256, 256, 0, stream>>>(W1, b1, W2, b2, W1p, W2p, Wext);
    init_out<<<(3 * NNODES + 255) / 256, 256, 0, stream>>>(coord, out, 3 * NNODES);

    if (ws_size >= need) {
        convert_h<<<(NNODES * HID / 8 + 255) / 256, 256, 0, stream>>>(h, h2);
        edge_kernel<true><<<E_EDGES / 128, 256, 0, stream>>>(h, h2, ei, cdiff, eattr,
                                                             (const ushortx8*)W1p, (const ushortx8*)W2p,
                                                             (const float4*)Wext, W3, out);
    } else {
        edge_kernel<false><<<E_EDGES / 128, 256, 0, stream>>>(h, h2, ei, cdiff, eattr,
                                                              (const ushortx8*)W1p, (const ushortx8*)W2p,
                                                              (const float4*)Wext, W3, out);
    }
}

// Round 4
// 301.380 us; speedup vs baseline: 1.5875x; 1.5854x over previous
//
#include <hip/hip_runtime.h>
#include <hip/hip_bf16.h>

#define E_EDGES 800000
#define NNODES  50000
#define HID     128

typedef __bf16 bf16x8 __attribute__((ext_vector_type(8)));
typedef float  f32x4  __attribute__((ext_vector_type(4)));
typedef unsigned short ushortx8 __attribute__((ext_vector_type(8)));

__device__ __forceinline__ unsigned short f2bf(float f) {   // RTNE
    union { float f; unsigned u; } v; v.f = f;
    unsigned r = v.u + 0x7FFFu + ((v.u >> 16) & 1u);
    return (unsigned short)(r >> 16);
}
__device__ __forceinline__ unsigned short f2bf_fast(float f) { // round-half-up
    union { float f; unsigned u; } v; v.f = f;
    return (unsigned short)((v.u + 0x8000u) >> 16);
}
__device__ __forceinline__ float bf2f(unsigned short u) {
    union { unsigned u; float f; } v; v.u = ((unsigned)u) << 16;
    return v.f;
}
__device__ __forceinline__ float silu(float x) {
    return x / (1.0f + __expf(-x));
}

// ---- weight packing ----
// W1p: B-frags for W1[:, :256], kc 0..7 (kc<4 = W1a/h[row], kc>=4 = W1b/h[col])
// W2p: B-frags for W2 with k in sigma-permuted order: position p holds feature
//      f = (p&7)*16 + (p>>3)
// Wext[c] = {W1[c][256], W1[c][257], b1[c], b2[c]}
// W3b2[c] = {W3[c], b2[c]}
// Eea[p]  = {W1[f][256], W1[f][257]}, f = sigma(p)  (edge-attr weights, p-order)
__global__ void pack_weights(const float* __restrict__ W1, const float* __restrict__ b1,
                             const float* __restrict__ W2, const float* __restrict__ b2,
                             const float* __restrict__ W3,
                             unsigned short* __restrict__ W1p, unsigned short* __restrict__ W2p,
                             float4* __restrict__ Wext, float2* __restrict__ W3b2,
                             float2* __restrict__ Eea) {
    int i = blockIdx.x * 256 + threadIdx.x;
    if (i < 32768) {
        int j = i & 7, lane = (i >> 3) & 63, nt = (i >> 9) & 7, kc = i >> 12;
        int n = lane & 15, quad = lane >> 4;
        int k = kc * 32 + quad * 8 + j;
        W1p[i] = f2bf(W1[(nt * 16 + n) * 258 + k]);
    } else if (i < 49152) {
        int t = i - 32768;
        int j = t & 7, lane = (t >> 3) & 63, nt = (t >> 9) & 7, kc = t >> 12;
        int n = lane & 15, quad = lane >> 4;
        int p = kc * 32 + quad * 8 + j;
        int f = (p & 7) * 16 + (p >> 3);
        W2p[t] = f2bf(W2[(nt * 16 + n) * 128 + f]);
    } else if (i < 49280) {
        int c = i - 49152;
        Wext[c] = make_float4(W1[c * 258 + 256], W1[c * 258 + 257], b1[c], b2[c]);
    } else if (i < 49408) {
        int c = i - 49280;
        W3b2[c] = make_float2(W3[c], b2[c]);
    } else if (i < 49536) {
        int p = i - 49408;
        int f = (p & 7) * 16 + (p >> 3);
        Eea[p] = make_float2(W1[f * 258 + 256], W1[f * 258 + 257]);
    }
}

// h (fp32) -> h2 (bf16)
__global__ void convert_h(const float* __restrict__ h, unsigned short* __restrict__ h2) {
    int i = blockIdx.x * 256 + threadIdx.x;   // 800000 threads
    const float4* p = (const float4*)(h + i * 8);
    float4 lo = p[0], hi = p[1];
    ushortx8 u;
    u[0] = f2bf(lo.x); u[1] = f2bf(lo.y); u[2] = f2bf(lo.z); u[3] = f2bf(lo.w);
    u[4] = f2bf(hi.x); u[5] = f2bf(hi.y); u[6] = f2bf(hi.z); u[7] = f2bf(hi.w);
    *(ushortx8*)(h2 + i * 8) = u;
}

__global__ void init_out(const float* __restrict__ coord, float* __restrict__ out, int n) {
    int i = blockIdx.x * 256 + threadIdx.x;
    if (i < n) out[i] = coord[i];
}

// PQb[node][p]: p<128 = P-half (h@W1a^T + b1), p>=128 = Q-half (h@W1b^T),
// both stored in sigma-permuted feature order: position p holds channel sigma(p).
__launch_bounds__(256)
__global__ void node_gemm(const unsigned short* __restrict__ h2,
                          const ushortx8* __restrict__ W1p,
                          const float4* __restrict__ Wext,
                          unsigned short* __restrict__ PQb) {
    const int half = blockIdx.y;               // 0 = P (W1a + b1), 1 = Q (W1b)
    const int w    = threadIdx.x >> 6;
    const int lane = threadIdx.x & 63;
    const int n    = lane & 15;
    const int quad = lane >> 4;
    const int base = (blockIdx.x * 4 + w) * 32;

    int nodeA[2];
#pragma unroll
    for (int mt = 0; mt < 2; ++mt) {
        int nd = base + mt * 16 + n;
        nodeA[mt] = nd < NNODES ? nd : NNODES - 1;
    }

    const f32x4 zero = { 0.f, 0.f, 0.f, 0.f };
    f32x4 acc[2][8];
#pragma unroll
    for (int mt = 0; mt < 2; ++mt)
#pragma unroll
        for (int nt = 0; nt < 8; ++nt) acc[mt][nt] = zero;

#pragma unroll
    for (int kc = 0; kc < 4; ++kc) {
        bf16x8 af[2];
#pragma unroll
        for (int mt = 0; mt < 2; ++mt)
            af[mt] = __builtin_bit_cast(bf16x8,
                *(const ushortx8*)(h2 + (long)nodeA[mt] * HID + kc * 32 + quad * 8));
#pragma unroll
        for (int nt = 0; nt < 8; ++nt) {
            bf16x8 bf = __builtin_bit_cast(bf16x8, W1p[((half * 4 + kc) * 8 + nt) * 64 + lane]);
            acc[0][nt] = __builtin_amdgcn_mfma_f32_16x16x32_bf16(af[0], bf, acc[0][nt], 0, 0, 0);
            acc[1][nt] = __builtin_amdgcn_mfma_f32_16x16x32_bf16(af[1], bf, acc[1][nt], 0, 0, 0);
        }
    }

    float b1v[8];
#pragma unroll
    for (int nt = 0; nt < 8; ++nt) b1v[nt] = (half == 0) ? Wext[nt * 16 + n].z : 0.f;

#pragma unroll
    for (int mt = 0; mt < 2; ++mt) {
#pragma unroll
        for (int r = 0; r < 4; ++r) {
            int node = base + mt * 16 + quad * 4 + r;
            if (node < NNODES) {
                ushortx8 u;
#pragma unroll
                for (int nt = 0; nt < 8; ++nt)
                    u[nt] = f2bf(acc[mt][nt][r] + b1v[nt]);   // stored at p = n*8+nt
                *(ushortx8*)(PQb + (long)node * 256 + half * 128 + n * 8) = u;
            }
        }
    }
}

// Per-edge: silu(P[row]+Q[col]+ea.w) -> layer2 MFMA -> layer3 dot -> tanh -> atomics.
// M=16 edges/wave, no LDS, no barriers.
__launch_bounds__(256, 4)
__global__ void edge16(const unsigned short* __restrict__ PQb,
                       const int* __restrict__ ei,
                       const float* __restrict__ cdiff,
                       const float2* __restrict__ eattr,
                       const ushortx8* __restrict__ W2p,
                       const float4* __restrict__ Eea4,
                       const float2* __restrict__ W3b2,
                       float* __restrict__ out) {
    const int wv   = threadIdx.x >> 6;
    const int lane = threadIdx.x & 63;
    const int n    = lane & 15;
    const int quad = lane >> 4;
    const int ebase = (blockIdx.x * 4 + wv) * 16;
    const int el = ebase + n;

    const int ri = ei[el];
    const int ci = ei[E_EDGES + el];
    const float2 ea = eattr[el];

    const unsigned short* Pb = PQb + (long)ri * 256 + quad * 8;
    const unsigned short* Qb = PQb + (long)ci * 256 + 128 + quad * 8;

    // issue all gathers upfront (independent; 4 kc from same row base, imm offsets)
    ushortx8 pf[4], qf[4];
#pragma unroll
    for (int kc = 0; kc < 4; ++kc) {
        pf[kc] = *(const ushortx8*)(Pb + kc * 32);
        qf[kc] = *(const ushortx8*)(Qb + kc * 32);
    }

    const f32x4 zero = { 0.f, 0.f, 0.f, 0.f };
    f32x4 acc[8];
#pragma unroll
    for (int nt = 0; nt < 8; ++nt) acc[nt] = zero;

#pragma unroll
    for (int kc = 0; kc < 4; ++kc) {
        float4 ef[4];
#pragma unroll
        for (int t = 0; t < 4; ++t) ef[t] = Eea4[kc * 16 + quad * 4 + t];
        ushortx8 u;
#pragma unroll
        for (int j = 0; j < 8; ++j) {
            float ex = (j & 1) ? ef[j >> 1].z : ef[j >> 1].x;
            float ey = (j & 1) ? ef[j >> 1].w : ef[j >> 1].y;
            float v = bf2f(pf[kc][j]) + bf2f(qf[kc][j]) + ea.x * ex + ea.y * ey;
            u[j] = f2bf_fast(silu(v));
        }
        bf16x8 af = __builtin_bit_cast(bf16x8, u);
#pragma unroll
        for (int nt = 0; nt < 8; ++nt) {
            bf16x8 bf = __builtin_bit_cast(bf16x8, W2p[(kc * 8 + nt) * 64 + lane]);
            acc[nt] = __builtin_amdgcn_mfma_f32_16x16x32_bf16(af, bf, acc[nt], 0, 0, 0);
        }
    }

    // layer 3: silu(acc + b2) . W3
    float part[4] = { 0.f, 0.f, 0.f, 0.f };
#pragma unroll
    for (int nt = 0; nt < 8; ++nt) {
        float2 wb = W3b2[nt * 16 + n];   // {W3, b2}
#pragma unroll
        for (int r = 0; r < 4; ++r)
            part[r] += silu(acc[nt][r] + wb.y) * wb.x;
    }
#pragma unroll
    for (int mask = 1; mask < 16; mask <<= 1)
#pragma unroll
        for (int r = 0; r < 4; ++r)
            part[r] += __shfl_xor(part[r], mask, 64);

    // lane l<16 takes part[l&3] from lane (l>>2)*16  (edge l has quad=l>>2, r=l&3)
    float s = 0.f;
#pragma unroll
    for (int r = 0; r < 4; ++r) {
        float t = __shfl(part[r], ((lane & 15) >> 2) * 16, 64);
        if ((lane & 3) == r) s = t;
    }

    if (lane < 16) {
        float ex2 = __expf(2.0f * s);
        float t = (1.0f - 2.0f / (ex2 + 1.0f)) * 0.15f;   // tanh(s) * 15/100
        float c0 = cdiff[3 * (long)el + 0];
        float c1 = cdiff[3 * (long)el + 1];
        float c2 = cdiff[3 * (long)el + 2];
        atomicAdd(&out[ri * 3 + 0], c0 * t);
        atomicAdd(&out[ri * 3 + 1], c1 * t);
        atomicAdd(&out[ri * 3 + 2], c2 * t);
    }
}

// ---- fallback (round-3 structure, fp32 h gather) if ws is too small ----
__launch_bounds__(256)
__global__ void edge_fb(const float* __restrict__ h, const int* __restrict__ ei,
                        const float* __restrict__ cdiff, const float* __restrict__ eattr,
                        const ushortx8* __restrict__ W1p, const ushortx8* __restrict__ W2p,
                        const float4* __restrict__ Wext, const float* __restrict__ W3,
                        float* __restrict__ out) {
    __shared__ __align__(16) unsigned short x1[4][32][136];
    __shared__ int   rowi[4][32];
    __shared__ int   coli[4][32];
    __shared__ float ea0[4][32];
    __shared__ float ea1[4][32];
    __shared__ float sbuf[4][32];

    const int w = threadIdx.x >> 6, lane = threadIdx.x & 63;
    const int n = lane & 15, quad = lane >> 4;
    const int ebase = (blockIdx.x * 4 + w) * 32;

    if (lane < 32) {
        int e = ebase + lane;
        rowi[w][lane] = ei[e];
        coli[w][lane] = ei[E_EDGES + e];
        const float2 ea = *(const float2*)(eattr + 2 * (long)e);
        ea0[w][lane] = ea.x; ea1[w][lane] = ea.y;
    }
    __syncthreads();

    int nodeR[2] = { rowi[w][n], rowi[w][16 + n] };
    int nodeC[2] = { coli[w][n], coli[w][16 + n] };

    const f32x4 zero = { 0.f, 0.f, 0.f, 0.f };
    f32x4 acc[2][8];
#pragma unroll
    for (int mt = 0; mt < 2; ++mt)
#pragma unroll
        for (int nt = 0; nt < 8; ++nt) acc[mt][nt] = zero;

#pragma unroll
    for (int kc = 0; kc < 8; ++kc) {
        bf16x8 afrag[2];
#pragma unroll
        for (int mt = 0; mt < 2; ++mt) {
            int node = (kc < 4) ? nodeR[mt] : nodeC[mt];
            const float* p = h + (long)node * HID + (kc & 3) * 32 + quad * 8;
            float4 lo = *(const float4*)p;
            float4 hi = *(const float4*)(p + 4);
            ushortx8 u;
            u[0] = f2bf(lo.x); u[1] = f2bf(lo.y); u[2] = f2bf(lo.z); u[3] = f2bf(lo.w);
            u[4] = f2bf(hi.x); u[5] = f2bf(hi.y); u[6] = f2bf(hi.z); u[7] = f2bf(hi.w);
            afrag[mt] = __builtin_bit_cast(bf16x8, u);
        }
#pragma unroll
        for (int nt = 0; nt < 8; ++nt) {
            bf16x8 bfrag = __builtin_bit_cast(bf16x8, W1p[(kc * 8 + nt) * 64 + lane]);
            acc[0][nt] = __builtin_amdgcn_mfma_f32_16x16x32_bf16(afrag[0], bfrag, acc[0][nt], 0, 0, 0);
            acc[1][nt] = __builtin_amdgcn_mfma_f32_16x16x32_bf16(afrag[1], bfrag, acc[1][nt], 0, 0, 0);
        }
    }

    float b2v[8];
    {
        float4 wx[8];
#pragma unroll
        for (int nt = 0; nt < 8; ++nt) wx[nt] = Wext[nt * 16 + n];
#pragma unroll
        for (int nt = 0; nt < 8; ++nt) b2v[nt] = wx[nt].w;
#pragma unroll
        for (int mt = 0; mt < 2; ++mt) {
#pragma unroll
            for (int r = 0; r < 4; ++r) {
                int m = mt * 16 + quad * 4 + r;
                float a0 = ea0[w][m], a1 = ea1[w][m];
                ushortx8 u;
#pragma unroll
                for (int nt = 0; nt < 8; ++nt) {
                    float v = acc[mt][nt][r] + wx[nt].z + a0 * wx[nt].x + a1 * wx[nt].y;
                    u[nt] = f2bf(silu(v));
                }
                *(ushortx8*)&x1[w][m][n * 8] = u;
            }
        }
    }
    __syncthreads();

#pragma unroll
    for (int mt = 0; mt < 2; ++mt)
#pragma unroll
        for (int nt = 0; nt < 8; ++nt) acc[mt][nt] = zero;

#pragma unroll
    for (int kc = 0; kc < 4; ++kc) {
        bf16x8 afrag[2];
#pragma unroll
        for (int mt = 0; mt < 2; ++mt)
            afrag[mt] = __builtin_bit_cast(bf16x8, *(const ushortx8*)&x1[w][mt * 16 + n][kc * 32 + quad * 8]);
#pragma unroll
        for (int nt = 0; nt < 8; ++nt) {
            bf16x8 bfrag = __builtin_bit_cast(bf16x8, W2p[(kc * 8 + nt) * 64 + lane]);
            acc[0][nt] = __builtin_amdgcn_mfma_f32_16x16x32_bf16(afrag[0], bfrag, acc[0][nt], 0, 0, 0);
            acc[1][nt] = __builtin_amdgcn_mfma_f32_16x16x32_bf16(afrag[1], bfrag, acc[1][nt], 0, 0, 0);
        }
    }

    float part[2][4] = { {0.f,0.f,0.f,0.f}, {0.f,0.f,0.f,0.f} };
#pragma unroll
    for (int nt = 0; nt < 8; ++nt) {
        float w3 = W3[nt * 16 + n];
#pragma unroll
        for (int mt = 0; mt < 2; ++mt)
#pragma unroll
            for (int r = 0; r < 4; ++r)
                part[mt][r] += silu(acc[mt][nt][r] + b2v[nt]) * w3;
    }
#pragma unroll
    for (int mask = 1; mask < 16; mask <<= 1)
#pragma unroll
        for (int mt = 0; mt < 2; ++mt)
#pragma unroll
            for (int r = 0; r < 4; ++r)
                part[mt][r] += __shfl_xor(part[mt][r], mask, 64);

    if (n == 0) {
#pragma unroll
        for (int mt = 0; mt < 2; ++mt)
#pragma unroll
            for (int r = 0; r < 4; ++r)
                sbuf[w][mt * 16 + quad * 4 + r] = part[mt][r];
    }
    __syncthreads();

    if (lane < 32) {
        int e = ebase + lane;
        float s = sbuf[w][lane];
        float ex = __expf(2.0f * s);
        float t = (1.0f - 2.0f / (ex + 1.0f)) * 0.15f;
        float c0 = cdiff[3 * (long)e + 0];
        float c1 = cdiff[3 * (long)e + 1];
        float c2 = cdiff[3 * (long)e + 2];
        int r = rowi[w][lane];
        atomicAdd(&out[r * 3 + 0], c0 * t);
        atomicAdd(&out[r * 3 + 1], c1 * t);
        atomicAdd(&out[r * 3 + 2], c2 * t);
    }
}

extern "C" void kernel_launch(void* const* d_in, const int* in_sizes, int n_in,
                              void* d_out, int out_size, void* d_ws, size_t ws_size,
                              hipStream_t stream) {
    const float* h     = (const float*)d_in[0];
    const float* coord = (const float*)d_in[1];
    const int*   ei    = (const int*)d_in[2];
    const float* cdiff = (const float*)d_in[3];
    const float* eattr = (const float*)d_in[4];
    const float* W1    = (const float*)d_in[5];
    const float* b1    = (const float*)d_in[6];
    const float* W2    = (const float*)d_in[7];
    const float* b2    = (const float*)d_in[8];
    const float* W3    = (const float*)d_in[9];
    float* out = (float*)d_out;

    char* ws = (char*)d_ws;
    unsigned short* W1p  = (unsigned short*)ws;                  // 65536 B
    unsigned short* W2p  = (unsigned short*)(ws + 65536);        // 32768 B
    float4*         Wext = (float4*)(ws + 98304);                // 2048 B
    float2*         W3b2 = (float2*)(ws + 100352);               // 1024 B
    float2*         Eea  = (float2*)(ws + 101376);               // 1024 B
    unsigned short* h2   = (unsigned short*)(ws + 102400);       // 12.8 MB
    unsigned short* PQb  = (unsigned short*)(ws + 102400 + 12800000); // 25.6 MB
    const size_t need_full = 102400ull + 12800000ull + 25600000ull;

    pack_weights<<<(49536 + 255) / 256, 256, 0, stream>>>(W1, b1, W2, b2, W3,
                                                          W1p, W2p, Wext, W3b2, Eea);
    init_out<<<(3 * NNODES + 255) / 256, 256, 0, stream>>>(coord, out, 3 * NNODES);

    if (ws_size >= need_full) {
        convert_h<<<(NNODES * HID / 8 + 255) / 256, 256, 0, stream>>>(h, h2);
        dim3 ngrid((NNODES + 127) / 128, 2);
        node_gemm<<<ngrid, 256, 0, stream>>>(h2, (const ushortx8*)W1p, (const float4*)Wext, PQb);
        edge16<<<E_EDGES / 64, 256, 0, stream>>>(PQb, ei, cdiff, (const float2*)eattr,
                                                 (const ushortx8*)W2p, (const float4*)Eea,
                                                 (const float2*)W3b2, out);
    } else {
        edge_fb<<<E_EDGES / 128, 256, 0, stream>>>(h, ei, cdiff, eattr,
                                                   (const ushortx8*)W1p, (const ushortx8*)W2p,
                                                   (const float4*)Wext, W3, out);
    }
}

// Round 5
// 284.846 us; speedup vs baseline: 1.6797x; 1.0580x over previous
//
#include <hip/hip_runtime.h>
#include <hip/hip_bf16.h>

#define E_EDGES 800000
#define NNODES  50000
#define HID     128

typedef __bf16 bf16x8 __attribute__((ext_vector_type(8)));
typedef float  f32x4  __attribute__((ext_vector_type(4)));
typedef unsigned short ushortx8 __attribute__((ext_vector_type(8)));

__device__ __forceinline__ unsigned short f2bf(float f) {   // RTNE
    union { float f; unsigned u; } v; v.f = f;
    unsigned r = v.u + 0x7FFFu + ((v.u >> 16) & 1u);
    return (unsigned short)(r >> 16);
}
__device__ __forceinline__ unsigned short f2bf_fast(float f) { // round-half-up
    union { float f; unsigned u; } v; v.f = f;
    return (unsigned short)((v.u + 0x8000u) >> 16);
}
__device__ __forceinline__ float bf2f(unsigned short u) {
    union { unsigned u; float f; } v; v.u = ((unsigned)u) << 16;
    return v.f;
}
// silu without the IEEE-divide expansion (v_div_scale/fmas/fixup ~9 ops):
// v_mul, v_exp, v_add, v_rcp, v_mul = 5 ops, 1-ulp rcp.
__device__ __forceinline__ float silu_fast(float x) {
    float e = __expf(-x);
    return x * __builtin_amdgcn_rcpf(1.0f + e);
}

// ---- prep: weight packing + out:=coord, one kernel ----
// W1p: B-frags for W1[:, :256], kc 0..7 (kc<4 = W1a/h[row], kc>=4 = W1b/h[col])
// W2p: B-frags for W2, k in sigma-permuted order (position p holds f=(p&7)*16+(p>>3))
// Wext[c] = {W1[c][256], W1[c][257], b1[c], b2[c]}
// W3b2[c] = {W3[c], b2[c]}
// Eea[p]  = {W1[f][256], W1[f][257]}, f = sigma(p)
__global__ void prep(const float* __restrict__ W1, const float* __restrict__ b1,
                     const float* __restrict__ W2, const float* __restrict__ b2,
                     const float* __restrict__ W3,
                     const float* __restrict__ coord, float* __restrict__ out,
                     unsigned short* __restrict__ W1p, unsigned short* __restrict__ W2p,
                     float4* __restrict__ Wext, float2* __restrict__ W3b2,
                     float2* __restrict__ Eea) {
    int i = blockIdx.x * 256 + threadIdx.x;
    if (i < 3 * NNODES) out[i] = coord[i];
    if (i < 32768) {
        int j = i & 7, lane = (i >> 3) & 63, nt = (i >> 9) & 7, kc = i >> 12;
        int n = lane & 15, quad = lane >> 4;
        int k = kc * 32 + quad * 8 + j;
        W1p[i] = f2bf(W1[(nt * 16 + n) * 258 + k]);
    } else if (i < 49152) {
        int t = i - 32768;
        int j = t & 7, lane = (t >> 3) & 63, nt = (t >> 9) & 7, kc = t >> 12;
        int n = lane & 15, quad = lane >> 4;
        int p = kc * 32 + quad * 8 + j;
        int f = (p & 7) * 16 + (p >> 3);
        W2p[t] = f2bf(W2[(nt * 16 + n) * 128 + f]);
    } else if (i < 49280) {
        int c = i - 49152;
        Wext[c] = make_float4(W1[c * 258 + 256], W1[c * 258 + 257], b1[c], b2[c]);
    } else if (i < 49408) {
        int c = i - 49280;
        W3b2[c] = make_float2(W3[c], b2[c]);
    } else if (i < 49536) {
        int p = i - 49408;
        int f = (p & 7) * 16 + (p >> 3);
        Eea[p] = make_float2(W1[f * 258 + 256], W1[f * 258 + 257]);
    }
}

// PQb[node][p]: p<128 = P-half (h@W1a^T + b1), p>=128 = Q-half (h@W1b^T),
// sigma-permuted feature order. fp32 h converted to bf16 in-register.
__launch_bounds__(256)
__global__ void node_gemm(const float* __restrict__ h,
                          const ushortx8* __restrict__ W1p,
                          const float4* __restrict__ Wext,
                          unsigned short* __restrict__ PQb) {
    const int half = blockIdx.y;               // 0 = P (W1a + b1), 1 = Q (W1b)
    const int w    = threadIdx.x >> 6;
    const int lane = threadIdx.x & 63;
    const int n    = lane & 15;
    const int quad = lane >> 4;
    const int base = (blockIdx.x * 4 + w) * 32;

    int nodeA[2];
#pragma unroll
    for (int mt = 0; mt < 2; ++mt) {
        int nd = base + mt * 16 + n;
        nodeA[mt] = nd < NNODES ? nd : NNODES - 1;
    }

    const f32x4 zero = { 0.f, 0.f, 0.f, 0.f };
    f32x4 acc[2][8];
#pragma unroll
    for (int mt = 0; mt < 2; ++mt)
#pragma unroll
        for (int nt = 0; nt < 8; ++nt) acc[mt][nt] = zero;

#pragma unroll
    for (int kc = 0; kc < 4; ++kc) {
        bf16x8 af[2];
#pragma unroll
        for (int mt = 0; mt < 2; ++mt) {
            const float* p = h + (long)nodeA[mt] * HID + kc * 32 + quad * 8;
            float4 lo = *(const float4*)p;
            float4 hi = *(const float4*)(p + 4);
            ushortx8 u;
            u[0] = f2bf(lo.x); u[1] = f2bf(lo.y); u[2] = f2bf(lo.z); u[3] = f2bf(lo.w);
            u[4] = f2bf(hi.x); u[5] = f2bf(hi.y); u[6] = f2bf(hi.z); u[7] = f2bf(hi.w);
            af[mt] = __builtin_bit_cast(bf16x8, u);
        }
#pragma unroll
        for (int nt = 0; nt < 8; ++nt) {
            bf16x8 bf = __builtin_bit_cast(bf16x8, W1p[((half * 4 + kc) * 8 + nt) * 64 + lane]);
            acc[0][nt] = __builtin_amdgcn_mfma_f32_16x16x32_bf16(af[0], bf, acc[0][nt], 0, 0, 0);
            acc[1][nt] = __builtin_amdgcn_mfma_f32_16x16x32_bf16(af[1], bf, acc[1][nt], 0, 0, 0);
        }
    }

    float b1v[8];
#pragma unroll
    for (int nt = 0; nt < 8; ++nt) b1v[nt] = (half == 0) ? Wext[nt * 16 + n].z : 0.f;

#pragma unroll
    for (int mt = 0; mt < 2; ++mt) {
#pragma unroll
        for (int r = 0; r < 4; ++r) {
            int node = base + mt * 16 + quad * 4 + r;
            if (node < NNODES) {
                ushortx8 u;
#pragma unroll
                for (int nt = 0; nt < 8; ++nt)
                    u[nt] = f2bf(acc[mt][nt][r] + b1v[nt]);   // stored at p = n*8+nt
                *(ushortx8*)(PQb + (long)node * 256 + half * 128 + n * 8) = u;
            }
        }
    }
}

// Per-edge: silu(P[row]+Q[col]+ea.w) -> layer2 MFMA -> layer3 dot -> tanh -> atomics.
// M=16 edges/wave, no LDS, no barriers.
__launch_bounds__(256, 4)
__global__ void edge16(const unsigned short* __restrict__ PQb,
                       const int* __restrict__ ei,
                       const float* __restrict__ cdiff,
                       const float2* __restrict__ eattr,
                       const ushortx8* __restrict__ W2p,
                       const float4* __restrict__ Eea4,
                       const float2* __restrict__ W3b2,
                       float* __restrict__ out) {
    const int wv   = threadIdx.x >> 6;
    const int lane = threadIdx.x & 63;
    const int n    = lane & 15;
    const int quad = lane >> 4;
    const int ebase = (blockIdx.x * 4 + wv) * 16;
    const int el = ebase + n;

    const int ri = ei[el];
    const int ci = ei[E_EDGES + el];
    const float2 ea = eattr[el];

    const unsigned short* Pb = PQb + (long)ri * 256 + quad * 8;
    const unsigned short* Qb = PQb + (long)ci * 256 + 128 + quad * 8;

    ushortx8 pf[4], qf[4];
#pragma unroll
    for (int kc = 0; kc < 4; ++kc) {
        pf[kc] = *(const ushortx8*)(Pb + kc * 32);
        qf[kc] = *(const ushortx8*)(Qb + kc * 32);
    }

    const f32x4 zero = { 0.f, 0.f, 0.f, 0.f };
    f32x4 acc[8];
#pragma unroll
    for (int nt = 0; nt < 8; ++nt) acc[nt] = zero;

#pragma unroll
    for (int kc = 0; kc < 4; ++kc) {
        float4 ef[4];
#pragma unroll
        for (int t = 0; t < 4; ++t) ef[t] = Eea4[kc * 16 + quad * 4 + t];
        ushortx8 u;
#pragma unroll
        for (int j = 0; j < 8; ++j) {
            float ex = (j & 1) ? ef[j >> 1].z : ef[j >> 1].x;
            float ey = (j & 1) ? ef[j >> 1].w : ef[j >> 1].y;
            float v = bf2f(pf[kc][j]) + bf2f(qf[kc][j]) + ea.x * ex + ea.y * ey;
            u[j] = f2bf_fast(silu_fast(v));
        }
        bf16x8 af = __builtin_bit_cast(bf16x8, u);
#pragma unroll
        for (int nt = 0; nt < 8; ++nt) {
            bf16x8 bf = __builtin_bit_cast(bf16x8, W2p[(kc * 8 + nt) * 64 + lane]);
            acc[nt] = __builtin_amdgcn_mfma_f32_16x16x32_bf16(af, bf, acc[nt], 0, 0, 0);
        }
    }

    // layer 3: silu(acc + b2) . W3
    float part[4] = { 0.f, 0.f, 0.f, 0.f };
#pragma unroll
    for (int nt = 0; nt < 8; ++nt) {
        float2 wb = W3b2[nt * 16 + n];   // {W3, b2}
#pragma unroll
        for (int r = 0; r < 4; ++r)
            part[r] += silu_fast(acc[nt][r] + wb.y) * wb.x;
    }
#pragma unroll
    for (int mask = 1; mask < 16; mask <<= 1)
#pragma unroll
        for (int r = 0; r < 4; ++r)
            part[r] += __shfl_xor(part[r], mask, 64);

    // lane l<16 takes part[l&3] from lane (l>>2)*16  (edge l has quad=l>>2, r=l&3)
    float s = 0.f;
#pragma unroll
    for (int r = 0; r < 4; ++r) {
        float t = __shfl(part[r], ((lane & 15) >> 2) * 16, 64);
        if ((lane & 3) == r) s = t;
    }

    if (lane < 16) {
        float ex2 = __expf(2.0f * s);
        float t = (1.0f - 2.0f * __builtin_amdgcn_rcpf(ex2 + 1.0f)) * 0.15f; // tanh*0.15
        float c0 = cdiff[3 * (long)el + 0];
        float c1 = cdiff[3 * (long)el + 1];
        float c2 = cdiff[3 * (long)el + 2];
        atomicAdd(&out[ri * 3 + 0], c0 * t);
        atomicAdd(&out[ri * 3 + 1], c1 * t);
        atomicAdd(&out[ri * 3 + 2], c2 * t);
    }
}

// ---- fallback (if ws too small): round-3 structure, fp32 h gather ----
__launch_bounds__(256)
__global__ void edge_fb(const float* __restrict__ h, const int* __restrict__ ei,
                        const float* __restrict__ cdiff, const float* __restrict__ eattr,
                        const ushortx8* __restrict__ W1p, const ushortx8* __restrict__ W2p,
                        const float4* __restrict__ Wext, const float* __restrict__ W3,
                        float* __restrict__ out) {
    __shared__ __align__(16) unsigned short x1[4][32][136];
    __shared__ int   rowi[4][32];
    __shared__ int   coli[4][32];
    __shared__ float ea0[4][32];
    __shared__ float ea1[4][32];
    __shared__ float sbuf[4][32];

    const int w = threadIdx.x >> 6, lane = threadIdx.x & 63;
    const int n = lane & 15, quad = lane >> 4;
    const int ebase = (blockIdx.x * 4 + w) * 32;

    if (lane < 32) {
        int e = ebase + lane;
        rowi[w][lane] = ei[e];
        coli[w][lane] = ei[E_EDGES + e];
        const float2 ea = *(const float2*)(eattr + 2 * (long)e);
        ea0[w][lane] = ea.x; ea1[w][lane] = ea.y;
    }
    __syncthreads();

    int nodeR[2] = { rowi[w][n], rowi[w][16 + n] };
    int nodeC[2] = { coli[w][n], coli[w][16 + n] };

    const f32x4 zero = { 0.f, 0.f, 0.f, 0.f };
    f32x4 acc[2][8];
#pragma unroll
    for (int mt = 0; mt < 2; ++mt)
#pragma unroll
        for (int nt = 0; nt < 8; ++nt) acc[mt][nt] = zero;

#pragma unroll
    for (int kc = 0; kc < 8; ++kc) {
        bf16x8 afrag[2];
#pragma unroll
        for (int mt = 0; mt < 2; ++mt) {
            int node = (kc < 4) ? nodeR[mt] : nodeC[mt];
            const float* p = h + (long)node * HID + (kc & 3) * 32 + quad * 8;
            float4 lo = *(const float4*)p;
            float4 hi = *(const float4*)(p + 4);
            ushortx8 u;
            u[0] = f2bf(lo.x); u[1] = f2bf(lo.y); u[2] = f2bf(lo.z); u[3] = f2bf(lo.w);
            u[4] = f2bf(hi.x); u[5] = f2bf(hi.y); u[6] = f2bf(hi.z); u[7] = f2bf(hi.w);
            afrag[mt] = __builtin_bit_cast(bf16x8, u);
        }
#pragma unroll
        for (int nt = 0; nt < 8; ++nt) {
            bf16x8 bfrag = __builtin_bit_cast(bf16x8, W1p[(kc * 8 + nt) * 64 + lane]);
            acc[0][nt] = __builtin_amdgcn_mfma_f32_16x16x32_bf16(afrag[0], bfrag, acc[0][nt], 0, 0, 0);
            acc[1][nt] = __builtin_amdgcn_mfma_f32_16x16x32_bf16(afrag[1], bfrag, acc[1][nt], 0, 0, 0);
        }
    }

    float b2v[8];
    {
        float4 wx[8];
#pragma unroll
        for (int nt = 0; nt < 8; ++nt) wx[nt] = Wext[nt * 16 + n];
#pragma unroll
        for (int nt = 0; nt < 8; ++nt) b2v[nt] = wx[nt].w;
#pragma unroll
        for (int mt = 0; mt < 2; ++mt) {
#pragma unroll
            for (int r = 0; r < 4; ++r) {
                int m = mt * 16 + quad * 4 + r;
                float a0 = ea0[w][m], a1 = ea1[w][m];
                ushortx8 u;
#pragma unroll
                for (int nt = 0; nt < 8; ++nt) {
                    float v = acc[mt][nt][r] + wx[nt].z + a0 * wx[nt].x + a1 * wx[nt].y;
                    u[nt] = f2bf(silu_fast(v));
                }
                *(ushortx8*)&x1[w][m][n * 8] = u;
            }
        }
    }
    __syncthreads();

#pragma unroll
    for (int mt = 0; mt < 2; ++mt)
#pragma unroll
        for (int nt = 0; nt < 8; ++nt) acc[mt][nt] = zero;

#pragma unroll
    for (int kc = 0; kc < 4; ++kc) {
        bf16x8 afrag[2];
#pragma unroll
        for (int mt = 0; mt < 2; ++mt)
            afrag[mt] = __builtin_bit_cast(bf16x8, *(const ushortx8*)&x1[w][mt * 16 + n][kc * 32 + quad * 8]);
#pragma unroll
        for (int nt = 0; nt < 8; ++nt) {
            bf16x8 bfrag = __builtin_bit_cast(bf16x8, W2p[(kc * 8 + nt) * 64 + lane]);
            acc[0][nt] = __builtin_amdgcn_mfma_f32_16x16x32_bf16(afrag[0], bfrag, acc[0][nt], 0, 0, 0);
            acc[1][nt] = __builtin_amdgcn_mfma_f32_16x16x32_bf16(afrag[1], bfrag, acc[1][nt], 0, 0, 0);
        }
    }

    float part[2][4] = { {0.f,0.f,0.f,0.f}, {0.f,0.f,0.f,0.f} };
#pragma unroll
    for (int nt = 0; nt < 8; ++nt) {
        float w3 = W3[nt * 16 + n];
#pragma unroll
        for (int mt = 0; mt < 2; ++mt)
#pragma unroll
            for (int r = 0; r < 4; ++r)
                part[mt][r] += silu_fast(acc[mt][nt][r] + b2v[nt]) * w3;
    }
#pragma unroll
    for (int mask = 1; mask < 16; mask <<= 1)
#pragma unroll
        for (int mt = 0; mt < 2; ++mt)
#pragma unroll
            for (int r = 0; r < 4; ++r)
                part[mt][r] += __shfl_xor(part[mt][r], mask, 64);

    if (n == 0) {
#pragma unroll
        for (int mt = 0; mt < 2; ++mt)
#pragma unroll
            for (int r = 0; r < 4; ++r)
                sbuf[w][mt * 16 + quad * 4 + r] = part[mt][r];
    }
    __syncthreads();

    if (lane < 32) {
        int e = ebase + lane;
        float s = sbuf[w][lane];
        float ex = __expf(2.0f * s);
        float t = (1.0f - 2.0f * __builtin_amdgcn_rcpf(ex + 1.0f)) * 0.15f;
        float c0 = cdiff[3 * (long)e + 0];
        float c1 = cdiff[3 * (long)e + 1];
        float c2 = cdiff[3 * (long)e + 2];
        int r = rowi[w][lane];
        atomicAdd(&out[r * 3 + 0], c0 * t);
        atomicAdd(&out[r * 3 + 1], c1 * t);
        atomicAdd(&out[r * 3 + 2], c2 * t);
    }
}

extern "C" void kernel_launch(void* const* d_in, const int* in_sizes, int n_in,
                              void* d_out, int out_size, void* d_ws, size_t ws_size,
                              hipStream_t stream) {
    const float* h     = (const float*)d_in[0];
    const float* coord = (const float*)d_in[1];
    const int*   ei    = (const int*)d_in[2];
    const float* cdiff = (const float*)d_in[3];
    const float* eattr = (const float*)d_in[4];
    const float* W1    = (const float*)d_in[5];
    const float* b1    = (const float*)d_in[6];
    const float* W2    = (const float*)d_in[7];
    const float* b2    = (const float*)d_in[8];
    const float* W3    = (const float*)d_in[9];
    float* out = (float*)d_out;

    char* ws = (char*)d_ws;
    unsigned short* W1p  = (unsigned short*)ws;                  // 65536 B
    unsigned short* W2p  = (unsigned short*)(ws + 65536);        // 32768 B
    float4*         Wext = (float4*)(ws + 98304);                // 2048 B
    float2*         W3b2 = (float2*)(ws + 100352);               // 1024 B
    float2*         Eea  = (float2*)(ws + 101376);               // 1024 B
    unsigned short* PQb  = (unsigned short*)(ws + 102400);       // 25.6 MB
    const size_t need_full = 102400ull + 25600000ull;

    // prep covers both out-init (150000) and packing (49536)
    prep<<<(3 * NNODES + 255) / 256, 256, 0, stream>>>(W1, b1, W2, b2, W3, coord, out,
                                                       W1p, W2p, Wext, W3b2, Eea);

    if (ws_size >= need_full) {
        dim3 ngrid((NNODES + 127) / 128, 2);
        node_gemm<<<ngrid, 256, 0, stream>>>(h, (const ushortx8*)W1p, (const float4*)Wext, PQb);
        edge16<<<E_EDGES / 64, 256, 0, stream>>>(PQb, ei, cdiff, (const float2*)eattr,
                                                 (const ushortx8*)W2p, (const float4*)Eea,
                                                 (const float2*)W3b2, out);
    } else {
        edge_fb<<<E_EDGES / 128, 256, 0, stream>>>(h, ei, cdiff, eattr,
                                                   (const ushortx8*)W1p, (const ushortx8*)W2p,
                                                   (const float4*)Wext, W3, out);
    }
}